// Round 6
// baseline (467.531 us; speedup 1.0000x reference)
//
#include <hip/hip_runtime.h>
#include <hip/hip_bf16.h>
#include <stdint.h>

typedef __attribute__((ext_vector_type(8))) short short8;   // 8 bf16 (4 VGPRs)
typedef __attribute__((ext_vector_type(4))) float f32x4;

#define IN_DIM 128
#define OUT_DIM 128
#define NROWS 524288
#define THREADS 512
#define NBLOCKS 1024                          // 4 blocks/CU x 256 CU, all resident
#define ROWS_PER_BLOCK (NROWS / NBLOCKS)      // 512 rows
#define TILES 4                               // 4 x 128-row tiles per block

__device__ __forceinline__ ushort f2bf(float f) {
    __hip_bfloat16 h = __float2bfloat16(f);
    union { __hip_bfloat16 h; ushort u; } cv;
    cv.h = h;
    return cv.u;
}

// y[m][n] = sum_k x[m][k] * W[n][k] + b[n]
// Operand-swapped MFMA: A = W (from LDS), B = x. D[n][m]: lane l -> out row
// m = m0 + (l&15), cols nt*16 + (l>>4)*4 .. +4  => f32x4 stores.
// Persistent: 1024 blocks (all resident), W staged ONCE, then 4 tiles/wave
// with no barriers -> waves desync and keep the memory pipe full.
__global__ __launch_bounds__(THREADS, 8) void linear_kernel(
    const float* __restrict__ x,
    const float* __restrict__ wgt,
    const float* __restrict__ bias,
    float* __restrict__ out)
{
    // W in MFMA A-fragment order: entry g=(kk*8+nt)*64+lane holds 8 bf16 (16B)
    __shared__ short8 wlds[2048];   // 32 KiB

    const int t  = threadIdx.x;
    const int l  = t & 63;
    const int wv = t >> 6;      // wave id 0..7
    const int r  = l & 15;      // lane's batch row within the 16-row strip
    const int q  = l >> 4;      // quarter: out col = nt*16 + q*4 + reg

    // ---- stage W f32 -> bf16 fragments in LDS, ONCE (W is L2-resident) ----
    #pragma unroll
    for (int i = 0; i < 4; ++i) {
        int g  = i * THREADS + t;
        int kk = g >> 9, nt = (g >> 6) & 7, ln = g & 63;
        int row   = nt * 16 + (ln & 15);          // W output row n
        int kbase = kk * 32 + ((ln >> 4) << 3);
        const float* src = wgt + row * IN_DIM + kbase;
        f32x4 lo = *reinterpret_cast<const f32x4*>(src);
        f32x4 hi = *reinterpret_cast<const f32x4*>(src + 4);
        short8 v;
        v[0] = (short)f2bf(lo[0]); v[1] = (short)f2bf(lo[1]);
        v[2] = (short)f2bf(lo[2]); v[3] = (short)f2bf(lo[3]);
        v[4] = (short)f2bf(hi[0]); v[5] = (short)f2bf(hi[1]);
        v[6] = (short)f2bf(hi[2]); v[7] = (short)f2bf(hi[3]);
        wlds[g] = v;
    }

    __syncthreads();   // only barrier in the kernel; wlds read-only after

    const long base = (long)blockIdx.x * ROWS_PER_BLOCK + wv * 16 + r;

    for (int tt = 0; tt < TILES; ++tt) {
        const long m = base + tt * 128;               // this wave's row for lane
        const float* xp = x + m * IN_DIM + (q << 3);

        // load x tile: 8 x 16B per lane
        f32x4 xv[8];
        #pragma unroll
        for (int kk = 0; kk < 4; ++kk) {
            xv[2 * kk]     = *reinterpret_cast<const f32x4*>(xp + kk * 32);
            xv[2 * kk + 1] = *reinterpret_cast<const f32x4*>(xp + kk * 32 + 4);
        }

        // cvt to bf16 B-fragments
        short8 a[4];
        #pragma unroll
        for (int kk = 0; kk < 4; ++kk) {
            f32x4 lo = xv[2 * kk], hi = xv[2 * kk + 1];
            short8 v;
            v[0] = (short)f2bf(lo[0]); v[1] = (short)f2bf(lo[1]);
            v[2] = (short)f2bf(lo[2]); v[3] = (short)f2bf(lo[3]);
            v[4] = (short)f2bf(hi[0]); v[5] = (short)f2bf(hi[1]);
            v[6] = (short)f2bf(hi[2]); v[7] = (short)f2bf(hi[3]);
            a[kk] = v;
        }

        f32x4 acc[8];
        #pragma unroll
        for (int nt = 0; nt < 8; ++nt) acc[nt] = (f32x4)(0.0f);

        #pragma unroll
        for (int kk = 0; kk < 4; ++kk) {
            #pragma unroll
            for (int nt = 0; nt < 8; ++nt) {
                acc[nt] = __builtin_amdgcn_mfma_f32_16x16x32_bf16(
                    wlds[(kk * 8 + nt) * 64 + l], a[kk], acc[nt], 0, 0, 0);
            }
        }

        // epilogue: bias (L1/L2-resident) + vectorized stores
        float* op = out + m * OUT_DIM + (q << 2);
        #pragma unroll
        for (int nt = 0; nt < 8; ++nt) {
            f32x4 b4 = *reinterpret_cast<const f32x4*>(bias + nt * 16 + (q << 2));
            f32x4 v  = acc[nt] + b4;
            *reinterpret_cast<f32x4*>(op + nt * 16) = v;
        }
    }
}

extern "C" void kernel_launch(void* const* d_in, const int* in_sizes, int n_in,
                              void* d_out, int out_size, void* d_ws, size_t ws_size,
                              hipStream_t stream) {
    const float* x  = (const float*)d_in[0];
    const float* w  = (const float*)d_in[1];
    const float* b  = (const float*)d_in[2];
    float* out      = (float*)d_out;
    linear_kernel<<<dim3(NBLOCKS), dim3(THREADS), 0, stream>>>(x, w, b, out);
}

// Round 7
// 462.302 us; speedup vs baseline: 1.0113x; 1.0113x over previous
//
#include <hip/hip_runtime.h>
#include <hip/hip_bf16.h>
#include <stdint.h>

typedef __attribute__((ext_vector_type(8))) short short8;   // 8 bf16 (4 VGPRs)
typedef __attribute__((ext_vector_type(4))) float f32x4;

#define IN_DIM 128
#define OUT_DIM 128
#define NROWS 524288
#define THREADS 256
#define TILES 8                               // 8 x 64-row tile-passes per block
#define ROWS_PER_BLOCK (64 * TILES)           // 512
#define NBLOCKS (NROWS / ROWS_PER_BLOCK)      // 1024
#define NSTEP (TILES * 4)                     // 32 pipeline steps (tile x kk)
#define DEPTH 4                               // load prefetch depth (steps)

__device__ __forceinline__ ushort f2bf(float f) {
    __hip_bfloat16 h = __float2bfloat16(f);
    union { __hip_bfloat16 h; ushort u; } cv;
    cv.h = h;
    return cv.u;
}

// y[m][n] = sum_k x[m][k] * W[n][k] + b[n]
// Operand-swapped MFMA: A = W (from LDS), B = x. D[n][m]: lane l -> out row
// m = m0 + (l&15), cols nt*16 + (l>>4)*4 .. +4  => f32x4 NT stores.
//
// Flat software pipeline: 32 steps/wave (8 tiles x 4 k-slices). Each step:
//   cvt slice s (regs) -> issue loads for slice s+4 into the freed slot ->
//   8 MFMAs. Loads stay 4-deep in flight per wave => continuous HBM issue
//   (fill kernel proves ~3 busy waves/CU saturate BW; bursty phases were
//   the R4-R6 limiter). Bias staged in LDS, folded into acc init, so no
//   global loads drain the vmcnt pipeline at tile boundaries.
__global__ __launch_bounds__(THREADS, 4) void linear_kernel(
    const float* __restrict__ x,
    const float* __restrict__ wgt,
    const float* __restrict__ bias,
    float* __restrict__ out)
{
    // W in MFMA A-fragment order: entry g=(kk*8+nt)*64+lane holds 8 bf16 (16B)
    __shared__ short8 wlds[2048];   // 32 KiB
    __shared__ f32x4  blds[32];     // bias fragments: [nt*4+q] = bias[nt*16+q*4..+4]

    const int t  = threadIdx.x;
    const int l  = t & 63;
    const int wv = t >> 6;      // wave id 0..3
    const int r  = l & 15;      // lane's batch row within the 16-row strip
    const int q  = l >> 4;      // quarter: out col = nt*16 + q*4 + reg

    // ---- stage W f32 -> bf16 fragments in LDS (W is L2-resident: 64 KB) ----
    #pragma unroll
    for (int i = 0; i < 8; ++i) {
        int g  = i * THREADS + t;
        int kk = g >> 9, nt = (g >> 6) & 7, ln = g & 63;
        int row   = nt * 16 + (ln & 15);          // W output row n
        int kbase = kk * 32 + ((ln >> 4) << 3);
        const float* src = wgt + row * IN_DIM + kbase;
        f32x4 lo = *reinterpret_cast<const f32x4*>(src);
        f32x4 hi = *reinterpret_cast<const f32x4*>(src + 4);
        short8 v;
        v[0] = (short)f2bf(lo[0]); v[1] = (short)f2bf(lo[1]);
        v[2] = (short)f2bf(lo[2]); v[3] = (short)f2bf(lo[3]);
        v[4] = (short)f2bf(hi[0]); v[5] = (short)f2bf(hi[1]);
        v[6] = (short)f2bf(hi[2]); v[7] = (short)f2bf(hi[3]);
        wlds[g] = v;
    }
    if (t < 32)
        blds[t] = *reinterpret_cast<const f32x4*>(bias + (t >> 2) * 16 + (t & 3) * 4);

    __syncthreads();   // only barrier; wlds/blds read-only afterwards

    const long mbase = (long)blockIdx.x * ROWS_PER_BLOCK + wv * 16 + r;
    const float* xp0 = x + mbase * IN_DIM + (q << 3);

    // ---- pipeline prologue: preload steps 0..DEPTH-1 ----
    f32x4 xq[DEPTH][2];
    #pragma unroll
    for (int s = 0; s < DEPTH; ++s) {
        const float* p = xp0 + (s >> 2) * 64 * IN_DIM + (s & 3) * 32;
        xq[s][0] = *reinterpret_cast<const f32x4*>(p);
        xq[s][1] = *reinterpret_cast<const f32x4*>(p + 4);
    }

    f32x4 acc[8];

    // ---- 32-step steady-state (fully unrolled: all indices static) ----
    #pragma unroll
    for (int s = 0; s < NSTEP; ++s) {
        const int tt = s >> 2, kk = s & 3, slot = s & (DEPTH - 1);

        if (kk == 0) {   // acc init = bias fragments (LDS broadcast, lgkm path)
            #pragma unroll
            for (int nt = 0; nt < 8; ++nt) acc[nt] = blds[nt * 4 + q];
        }

        // cvt current slice BEFORE overwriting its slot
        f32x4 lo = xq[slot][0], hi = xq[slot][1];
        short8 a;
        a[0] = (short)f2bf(lo[0]); a[1] = (short)f2bf(lo[1]);
        a[2] = (short)f2bf(lo[2]); a[3] = (short)f2bf(lo[3]);
        a[4] = (short)f2bf(hi[0]); a[5] = (short)f2bf(hi[1]);
        a[6] = (short)f2bf(hi[2]); a[7] = (short)f2bf(hi[3]);

        // issue loads for step s+DEPTH into the freed slot (stays in flight
        // across the next ~4 compute steps; compiler emits counted vmcnt)
        if (s + DEPTH < NSTEP) {
            const int sp = s + DEPTH;
            const float* p = xp0 + (sp >> 2) * 64 * IN_DIM + (sp & 3) * 32;
            xq[slot][0] = *reinterpret_cast<const f32x4*>(p);
            xq[slot][1] = *reinterpret_cast<const f32x4*>(p + 4);
        }

        #pragma unroll
        for (int nt = 0; nt < 8; ++nt) {
            acc[nt] = __builtin_amdgcn_mfma_f32_16x16x32_bf16(
                wlds[(kk * 8 + nt) * 64 + l], a, acc[nt], 0, 0, 0);
        }

        if (kk == 3) {   // tile done: bias already in acc; NT vector stores
            float* op = out + (mbase + tt * 64) * OUT_DIM + (q << 2);
            #pragma unroll
            for (int nt = 0; nt < 8; ++nt) {
                __builtin_nontemporal_store(acc[nt],
                    reinterpret_cast<f32x4*>(op + nt * 16));
            }
        }
    }
}

extern "C" void kernel_launch(void* const* d_in, const int* in_sizes, int n_in,
                              void* d_out, int out_size, void* d_ws, size_t ws_size,
                              hipStream_t stream) {
    const float* x  = (const float*)d_in[0];
    const float* w  = (const float*)d_in[1];
    const float* b  = (const float*)d_in[2];
    float* out      = (float*)d_out;
    linear_kernel<<<dim3(NBLOCKS), dim3(THREADS), 0, stream>>>(x, w, b, out);
}